// Round 8
// baseline (2380.331 us; speedup 1.0000x reference)
//
#include <hip/hip_runtime.h>
#include <hip/hip_bf16.h>

typedef _Float16 half8 __attribute__((ext_vector_type(8)));
typedef _Float16 half4 __attribute__((ext_vector_type(4)));
typedef float f32x4 __attribute__((ext_vector_type(4)));

// Geometry: D=256, H=8, A=64, M=400000 (64*6250), N=50000
// Algebra: out_g = sum_h (u_{g,h}/s_{g,h}) @ (Wv_h @ Wout_h) + bout
//          u_{g,h} = sum_{m in g} e_{m,h} * msg_m   (weighted row sum)

// ---------------- wqkT: [16*64][256] f16 (q heads 0-7, k heads 8-15) ----------------
__global__ void k_convert(const float* __restrict__ Wq, const float* __restrict__ Wk,
                          _Float16* __restrict__ wqkT)
{
    int gid = blockIdx.x * 256 + threadIdx.x;   // 131072
    int h = gid >> 14;
    int d = (gid >> 6) & 255;
    int a = gid & 63;
    wqkT[((h * 64 + a) << 8) + d]       = (_Float16)Wq[gid];
    wqkT[(((8 + h) * 64 + a) << 8) + d] = (_Float16)Wk[gid];
}

// ---------------- CT[dout][h*256+din] = sum_a Wv[h][din][a]*Wout[h*64+a][dout] ----------------
__global__ void k_convC(const float* __restrict__ Wv, const float* __restrict__ Wout,
                        _Float16* __restrict__ CT)
{
    __shared__ float wv[4][64];
    int h = blockIdx.x >> 6, din0 = (blockIdx.x & 63) << 2;
    int t = threadIdx.x;
    wv[t >> 6][t & 63] = Wv[((h << 8) + din0 + (t >> 6)) * 64 + (t & 63)];
    __syncthreads();
    float s[4] = {0.f, 0.f, 0.f, 0.f};
    for (int a = 0; a < 64; ++a) {
        float wo = Wout[(h * 64 + a) * 256 + t];
        #pragma unroll
        for (int dd = 0; dd < 4; ++dd) s[dd] += wv[dd][a] * wo;
    }
    #pragma unroll
    for (int dd = 0; dd < 4; ++dd)
        CT[((long)t << 11) + (h << 8) + din0 + dd] = (_Float16)s[dd];
}

// ---------------- counting sort ----------------
__global__ void k_hist(const int* __restrict__ index, int* __restrict__ counts, int M) {
    int m = blockIdx.x * 256 + threadIdx.x;
    if (m < M) atomicAdd(&counts[index[m]], 1);
}

__global__ __launch_bounds__(1024) void k_scan1(const int* __restrict__ counts,
                                                int* __restrict__ starts,
                                                int* __restrict__ blocktot, int N) {
    __shared__ int s[1024];
    int b = blockIdx.x, t = threadIdx.x;
    int i = b * 1024 + t;
    int x = (i < N) ? counts[i] : 0;
    s[t] = x;
    __syncthreads();
    #pragma unroll
    for (int off = 1; off < 1024; off <<= 1) {
        int v = (t >= off) ? s[t - off] : 0;
        __syncthreads();
        s[t] += v;
        __syncthreads();
    }
    if (i < N) starts[i] = s[t] - x;
    if (t == 1023) blocktot[b] = s[1023];
}

__global__ void k_scan2(const int* __restrict__ blocktot, int* __restrict__ blockoff, int NC) {
    if (threadIdx.x == 0 && blockIdx.x == 0) {
        int run = 0;
        for (int i = 0; i < NC; ++i) { blockoff[i] = run; run += blocktot[i]; }
    }
}

__global__ __launch_bounds__(1024) void k_scan3(int* __restrict__ starts,
                                                int* __restrict__ cursor,
                                                const int* __restrict__ blockoff,
                                                int N, int M) {
    int b = blockIdx.x, t = threadIdx.x;
    int i = b * 1024 + t;
    if (i < N) {
        int v = starts[i] + blockoff[b];
        starts[i] = v;
        cursor[i] = v;
    }
    if (b == 0 && t == 0) starts[N] = M;
}

__global__ void k_scatteridx(const int* __restrict__ index, int* __restrict__ cursor,
                             int* __restrict__ sorted, int* __restrict__ segsorted, int M) {
    int m = blockIdx.x * 256 + threadIdx.x;
    if (m < M) {
        int idx = index[m];
        int pos = atomicAdd(&cursor[idx], 1);
        sorted[pos] = m;
        segsorted[pos] = idx;
    }
}

// ---------------- zero u rows of block-boundary segments (atomic targets) ----------------
__global__ __launch_bounds__(256) void k_zero_bnd(const int* __restrict__ segsorted,
                                                  float* __restrict__ u, int M) {
    long r0 = (long)blockIdx.x * 64;
    long rl = r0 + 63; if (rl > M - 1) rl = M - 1;
    int g0 = segsorted[r0];
    int g1 = segsorted[rl];
    int t = threadIdx.x;
    float4 z = {0.f, 0.f, 0.f, 0.f};
    float4* p0 = (float4*)(u + (long)g0 * 2048);
    float4* p1 = (float4*)(u + (long)g1 * 2048);
    p0[t] = z; p0[t + 256] = z;
    p1[t] = z; p1[t + 256] = z;
}

// ---------------- flush helper: by-value vector args stay in VGPRs ----------------
__device__ __forceinline__ void flush_u(float* __restrict__ u, float* __restrict__ segsum,
                                        int g, int gl0, int ghi, int h0, int l,
                                        f32x4 a0, f32x4 a1, float se0, float se1)
{
    bool bd = (g == gl0) || (g == ghi);
    float* d0 = u + (long)g * 2048 + h0 * 256 + l * 4;
    if (bd) {
        atomicAdd(d0 + 0, a0[0]); atomicAdd(d0 + 1, a0[1]);
        atomicAdd(d0 + 2, a0[2]); atomicAdd(d0 + 3, a0[3]);
        atomicAdd(d0 + 256, a1[0]); atomicAdd(d0 + 257, a1[1]);
        atomicAdd(d0 + 258, a1[2]); atomicAdd(d0 + 259, a1[3]);
    } else {
        *(f32x4*)d0 = a0;
        *(f32x4*)(d0 + 256) = a1;
    }
    if (l == 0) {
        float* ds = segsum + (long)g * 8 + h0;
        if (bd) { atomicAdd(ds, se0); atomicAdd(ds + 1, se1); }
        else { ds[0] = se0; ds[1] = se1; }
    }
}

// ---------------- fused: q,k scores -> e; weighted msg segment-sum ----------------
// Score phase: wave w owns rows w*16..w*16+15; loops all 8 heads (32-VGPR accs).
// wsum phase: wave w accumulates heads 2w,2w+1 over all 64 sorted rows.
__global__ __launch_bounds__(256) void k_score_wsum(
    const float* __restrict__ msg, const int* __restrict__ sorted,
    const int* __restrict__ segsorted, const _Float16* __restrict__ wqkT,
    float* __restrict__ u, float* __restrict__ segsum, int M)
{
    __shared__ _Float16 At[64 * 256];   // 32 KB, XOR-swizzled
    __shared__ float e_lds[64][8];      // 2 KB
    __shared__ int s_id[64];
    __shared__ int s_sg[64];
    char* lds = (char*)At;
    const int t = threadIdx.x;

    // bijective XCD-chunked swizzle (neighbor blocks share boundary segs -> same L2)
    int nwg = gridDim.x;
    int qc = nwg >> 3, rc = nwg & 7;
    int xcd = blockIdx.x & 7, ofs = blockIdx.x >> 3;
    int b = ((xcd < rc) ? xcd * (qc + 1) : rc * (qc + 1) + (xcd - rc) * qc) + ofs;
    const long m0 = (long)b * 64;

    if (t < 64) {
        s_id[t] = sorted[m0 + t];
        s_sg[t] = segsorted[m0 + t];
    }
    __syncthreads();

    // stage gathered 64x256 f32 -> f16 LDS
    const float4* msgf4 = (const float4*)msg;
    #pragma unroll
    for (int it = 0; it < 16; ++it) {
        int e4 = it * 256 + t;
        int row = e4 >> 6, c4 = e4 & 63;
        float4 v = msgf4[(long)s_id[row] * 64 + c4];
        half4 hv = {(_Float16)v.x, (_Float16)v.y, (_Float16)v.z, (_Float16)v.w};
        int bb = ((row << 9) + (c4 << 3)) ^ ((row & 7) << 4);
        *(half4*)(lds + bb) = hv;
    }
    __syncthreads();

    const int w = t >> 6, l = t & 63, lr = l & 15, lk = l >> 4;
    const f32x4 zero = {0.f, 0.f, 0.f, 0.f};
    const int arow = w * 16 + lr;

    // ---- scores ----
    #pragma unroll 1
    for (int h = 0; h < 8; ++h) {
        f32x4 aq0 = zero, aq1 = zero, aq2 = zero, aq3 = zero;
        f32x4 ak0 = zero, ak1 = zero, ak2 = zero, ak3 = zero;
        #pragma unroll
        for (int k0 = 0; k0 < 8; ++k0) {
            int ab = ((arow << 9) + ((k0 * 32 + lk * 8) << 1)) ^ ((arow & 7) << 4);
            half8 a = *(const half8*)(lds + ab);
            const _Float16* bq = wqkT + ((h * 64 + lr) << 8) + k0 * 32 + lk * 8;
            const _Float16* bk = wqkT + (((8 + h) * 64 + lr) << 8) + k0 * 32 + lk * 8;
            aq0 = __builtin_amdgcn_mfma_f32_16x16x32_f16(a, *(const half8*)(bq),          aq0, 0, 0, 0);
            ak0 = __builtin_amdgcn_mfma_f32_16x16x32_f16(a, *(const half8*)(bk),          ak0, 0, 0, 0);
            aq1 = __builtin_amdgcn_mfma_f32_16x16x32_f16(a, *(const half8*)(bq + 4096),   aq1, 0, 0, 0);
            ak1 = __builtin_amdgcn_mfma_f32_16x16x32_f16(a, *(const half8*)(bk + 4096),   ak1, 0, 0, 0);
            aq2 = __builtin_amdgcn_mfma_f32_16x16x32_f16(a, *(const half8*)(bq + 8192),   aq2, 0, 0, 0);
            ak2 = __builtin_amdgcn_mfma_f32_16x16x32_f16(a, *(const half8*)(bk + 8192),   ak2, 0, 0, 0);
            aq3 = __builtin_amdgcn_mfma_f32_16x16x32_f16(a, *(const half8*)(bq + 12288),  aq3, 0, 0, 0);
            ak3 = __builtin_amdgcn_mfma_f32_16x16x32_f16(a, *(const half8*)(bk + 12288),  ak3, 0, 0, 0);
        }
        f32x4 p = aq0 * ak0 + aq1 * ak1 + aq2 * ak2 + aq3 * ak3;
        #pragma unroll
        for (int off = 1; off < 16; off <<= 1) {
            p[0] += __shfl_xor(p[0], off);
            p[1] += __shfl_xor(p[1], off);
            p[2] += __shfl_xor(p[2], off);
            p[3] += __shfl_xor(p[3], off);
        }
        if (lr == 0) {
            #pragma unroll
            for (int j = 0; j < 4; ++j) {
                float s = p[j];
                s = (s >= 0.f) ? s : 0.2f * s;
                e_lds[w * 16 + lk * 4 + j][h] = __expf(s);  // |s|<~48 << 88: f32-safe
            }
        }
    }
    __syncthreads();

    // ---- weighted segment-sum: wave w -> heads 2w,2w+1; lane owns 4 msg cols ----
    const int gl0 = s_sg[0], ghi = s_sg[63];
    const int h0 = w * 2;
    f32x4 a0 = zero, a1 = zero;
    float se0 = 0.f, se1 = 0.f;
    int cur = gl0;

    #pragma unroll 4
    for (int row = 0; row < 64; ++row) {
        int sg = s_sg[row];
        if (sg != cur) {                 // wave-uniform branch
            flush_u(u, segsum, cur, gl0, ghi, h0, l, a0, a1, se0, se1);
            cur = sg; a0 = zero; a1 = zero; se0 = 0.f; se1 = 0.f;
        }
        int bb = ((row << 9) + (l << 3)) ^ ((row & 7) << 4);
        half4 mv = *(const half4*)(lds + bb);
        float e0 = e_lds[row][h0], e1 = e_lds[row][h0 + 1];
        float f0 = (float)mv[0], f1 = (float)mv[1], f2 = (float)mv[2], f3 = (float)mv[3];
        a0[0] += e0 * f0; a0[1] += e0 * f1; a0[2] += e0 * f2; a0[3] += e0 * f3;
        a1[0] += e1 * f0; a1[1] += e1 * f1; a1[2] += e1 * f2; a1[3] += e1 * f3;
        if (l == 0) { se0 += e0; se1 += e1; }
    }
    flush_u(u, segsum, cur, gl0, ghi, h0, l, a0, a1, se0, se1);
}

// ---------------- out = (u/segsum) @ CT^T + bout   (K=2048, chunk==head) ----------------
__global__ __launch_bounds__(256) void k_out2(
    const float* __restrict__ u, const float* __restrict__ segsum,
    const _Float16* __restrict__ CT, const float* __restrict__ bout,
    float* __restrict__ out, int N)
{
    __shared__ _Float16 At[64 * 256];   // 32 KB swizzled, per k-chunk
    char* lds = (char*)At;
    const int t = threadIdx.x;
    const long n0 = (long)blockIdx.x * 64;
    const int w = t >> 6, l = t & 63, lr = l & 15, lk = l >> 4;
    const f32x4 zero = {0.f, 0.f, 0.f, 0.f};

    f32x4 ac[4][4];
    #pragma unroll
    for (int r = 0; r < 4; ++r)
        #pragma unroll
        for (int n = 0; n < 4; ++n) ac[r][n] = zero;

    #pragma unroll 1
    for (int kc = 0; kc < 8; ++kc) {    // k-chunk == head
        __syncthreads();
        #pragma unroll
        for (int it = 0; it < 16; ++it) {
            int e4 = it * 256 + t;
            int row = e4 >> 6, c4 = e4 & 63;
            long gr = n0 + row;
            float4 v = {0.f, 0.f, 0.f, 0.f};
            float inv = 0.f;
            if (gr < N) {
                v = ((const float4*)u)[gr * 512 + kc * 64 + c4];
                float ss = segsum[gr * 8 + kc];
                inv = (ss > 0.f) ? 1.f / ss : 0.f;
            }
            half4 hv = {(_Float16)(v.x * inv), (_Float16)(v.y * inv),
                        (_Float16)(v.z * inv), (_Float16)(v.w * inv)};
            int bb = ((row << 9) + (c4 << 3)) ^ ((row & 7) << 4);
            *(half4*)(lds + bb) = hv;
        }
        __syncthreads();
        #pragma unroll
        for (int k0 = 0; k0 < 8; ++k0) {
            half8 a[4];
            #pragma unroll
            for (int r = 0; r < 4; ++r) {
                int row = r * 16 + lr;
                int bb = ((row << 9) + ((k0 * 32 + lk * 8) << 1)) ^ ((row & 7) << 4);
                a[r] = *(const half8*)(lds + bb);
            }
            #pragma unroll
            for (int n = 0; n < 4; ++n) {
                half8 bw = *(const half8*)(CT + ((long)(w * 64 + n * 16 + lr) << 11)
                                              + kc * 256 + k0 * 32 + lk * 8);
                #pragma unroll
                for (int r = 0; r < 4; ++r)
                    ac[r][n] = __builtin_amdgcn_mfma_f32_16x16x32_f16(a[r], bw, ac[r][n], 0, 0, 0);
            }
        }
    }
    #pragma unroll
    for (int n = 0; n < 4; ++n) {
        int col = w * 64 + n * 16 + lr;
        float bb = bout[col];
        #pragma unroll
        for (int r = 0; r < 4; ++r) {
            #pragma unroll
            for (int j = 0; j < 4; ++j) {
                long row = n0 + r * 16 + lk * 4 + j;
                if (row < N) out[row * 256 + col] = ac[r][n][j] + bb;
            }
        }
    }
}

extern "C" void kernel_launch(void* const* d_in, const int* in_sizes, int n_in,
                              void* d_out, int out_size, void* d_ws, size_t ws_size,
                              hipStream_t stream)
{
    const float* msg   = (const float*)d_in[0];
    const int*   index = (const int*)d_in[1];
    const float* Wq    = (const float*)d_in[4];
    const float* Wk    = (const float*)d_in[5];
    const float* Wv    = (const float*)d_in[6];
    const float* Wout  = (const float*)d_in[7];
    const float* bout  = (const float*)d_in[8];
    float* out = (float*)d_out;

    const int M = in_sizes[0] / 256;   // 400000
    const int N = out_size / 256;      // 50000
    const int NC = (N + 1023) / 1024;  // 49 scan chunks

    char* ws = (char*)d_ws;
    _Float16* wqkT = (_Float16*)(ws);              // 524288 B
    _Float16* CT   = (_Float16*)(ws + 524288);     // 1048576 B
    size_t o2 = 1572864;
    float* segsum = (float*)(ws + o2);                         // N*32
    int* counts   = (int*)(ws + o2 + (size_t)N * 32);          // N*4
    size_t uoff   = (o2 + (size_t)N * 36 + 255) & ~(size_t)255;
    float* u      = (float*)(ws + uoff);                       // N*8192
    size_t p2     = uoff + (size_t)N * 8192;
    int* cursor    = (int*)(ws + p2);                          // N*4
    int* starts    = (int*)(ws + p2 + (size_t)N * 4);          // (N+1)*4
    char* p3       = ws + p2 + (((size_t)N * 8 + 4 + 63) & ~(size_t)63);
    int* sorted    = (int*)(p3);                               // M*4
    int* segsorted = (int*)(p3 + (size_t)M * 4);               // M*4
    int* blocktot  = (int*)(p3 + (size_t)M * 8);               // 256 B
    int* blockoff  = (int*)(p3 + (size_t)M * 8 + 256);         // 256 B

    // zero only segsum + counts (1.8 MB); u boundary rows zeroed by k_zero_bnd,
    // empty-seg u rows are masked by inv=0 in k_out2 (poison is finite)
    hipMemsetAsync(ws + o2, 0, (size_t)N * 36, stream);

    k_convert<<<512, 256, 0, stream>>>(Wq, Wk, wqkT);
    k_convC<<<512, 256, 0, stream>>>(Wv, Wout, CT);
    k_hist<<<(M + 255) / 256, 256, 0, stream>>>(index, counts, M);
    k_scan1<<<NC, 1024, 0, stream>>>(counts, starts, blocktot, N);
    k_scan2<<<1, 64, 0, stream>>>(blocktot, blockoff, NC);
    k_scan3<<<NC, 1024, 0, stream>>>(starts, cursor, blockoff, N, M);
    k_scatteridx<<<(M + 255) / 256, 256, 0, stream>>>(index, cursor, sorted, segsorted, M);
    k_zero_bnd<<<M / 64, 256, 0, stream>>>(segsorted, u, M);
    k_score_wsum<<<M / 64, 256, 0, stream>>>(msg, sorted, segsorted, wqkT, u, segsum, M);
    k_out2<<<(N + 63) / 64, 256, 0, stream>>>(u, segsum, CT, bout, out, N);
}

// Round 9
// 1189.363 us; speedup vs baseline: 2.0014x; 2.0014x over previous
//
#include <hip/hip_runtime.h>
#include <hip/hip_bf16.h>

typedef _Float16 half8 __attribute__((ext_vector_type(8)));
typedef _Float16 half4 __attribute__((ext_vector_type(4)));
typedef float f32x4 __attribute__((ext_vector_type(4)));

// Geometry: D=256, H=8, A=64, M=400000 (128*3125), N=50000
// Algebra: out_g = sum_h (u_{g,h}/s_{g,h}) @ (Wv_h @ Wout_h) + bout
//          u_{g,h} = sum_{m in g} e_{m,h} * msg_m

#define MFMA16(a, b, c) __builtin_amdgcn_mfma_f32_16x16x32_f16(a, b, c, 0, 0, 0)

// ---------------- wqkT: [16*64][256] f16, rows PRE-XOR-SWIZZLED ----------------
// panel row a (0..63), element d stored at d ^ ((a&7)<<3): a LINEAR
// global_load_lds copy then yields the swizzled LDS layout the readers use.
__global__ void k_convert(const float* __restrict__ Wq, const float* __restrict__ Wk,
                          _Float16* __restrict__ wqkT)
{
    int gid = blockIdx.x * 256 + threadIdx.x;   // 131072
    int h = gid >> 14;
    int d = (gid >> 6) & 255;
    int a = gid & 63;
    int dq = d ^ ((a & 7) << 3);
    wqkT[((h * 64 + a) << 8) + dq]       = (_Float16)Wq[gid];
    wqkT[(((8 + h) * 64 + a) << 8) + dq] = (_Float16)Wk[gid];
}

// ---------------- CT[dout][h*256+din] = sum_a Wv[h][din][a]*Wout[h*64+a][dout] ----------------
__global__ void k_convC(const float* __restrict__ Wv, const float* __restrict__ Wout,
                        _Float16* __restrict__ CT)
{
    __shared__ float wv[4][64];
    int h = blockIdx.x >> 6, din0 = (blockIdx.x & 63) << 2;
    int t = threadIdx.x;
    wv[t >> 6][t & 63] = Wv[((h << 8) + din0 + (t >> 6)) * 64 + (t & 63)];
    __syncthreads();
    float s[4] = {0.f, 0.f, 0.f, 0.f};
    for (int a = 0; a < 64; ++a) {
        float wo = Wout[(h * 64 + a) * 256 + t];
        #pragma unroll
        for (int dd = 0; dd < 4; ++dd) s[dd] += wv[dd][a] * wo;
    }
    #pragma unroll
    for (int dd = 0; dd < 4; ++dd)
        CT[((long)t << 11) + (h << 8) + din0 + dd] = (_Float16)s[dd];
}

// ---------------- counting sort ----------------
__global__ void k_hist(const int* __restrict__ index, int* __restrict__ counts, int M) {
    int m = blockIdx.x * 256 + threadIdx.x;
    if (m < M) atomicAdd(&counts[index[m]], 1);
}

__global__ __launch_bounds__(1024) void k_scan1(const int* __restrict__ counts,
                                                int* __restrict__ starts,
                                                int* __restrict__ blocktot, int N) {
    __shared__ int s[1024];
    int b = blockIdx.x, t = threadIdx.x;
    int i = b * 1024 + t;
    int x = (i < N) ? counts[i] : 0;
    s[t] = x;
    __syncthreads();
    #pragma unroll
    for (int off = 1; off < 1024; off <<= 1) {
        int v = (t >= off) ? s[t - off] : 0;
        __syncthreads();
        s[t] += v;
        __syncthreads();
    }
    if (i < N) starts[i] = s[t] - x;
    if (t == 1023) blocktot[b] = s[1023];
}

__global__ void k_scan2(const int* __restrict__ blocktot, int* __restrict__ blockoff, int NC) {
    if (threadIdx.x == 0 && blockIdx.x == 0) {
        int run = 0;
        for (int i = 0; i < NC; ++i) { blockoff[i] = run; run += blocktot[i]; }
    }
}

__global__ __launch_bounds__(1024) void k_scan3(int* __restrict__ starts,
                                                int* __restrict__ cursor,
                                                const int* __restrict__ blockoff,
                                                int N, int M) {
    int b = blockIdx.x, t = threadIdx.x;
    int i = b * 1024 + t;
    if (i < N) {
        int v = starts[i] + blockoff[b];
        starts[i] = v;
        cursor[i] = v;
    }
    if (b == 0 && t == 0) starts[N] = M;
}

__global__ void k_scatteridx(const int* __restrict__ index, int* __restrict__ cursor,
                             int* __restrict__ sorted, int* __restrict__ segsorted, int M) {
    int m = blockIdx.x * 256 + threadIdx.x;
    if (m < M) {
        int idx = index[m];
        int pos = atomicAdd(&cursor[idx], 1);
        sorted[pos] = m;
        segsorted[pos] = idx;
    }
}

// ---------------- zero u rows of block-boundary segments (atomic targets) ----------------
__global__ __launch_bounds__(256) void k_zero_bnd(const int* __restrict__ segsorted,
                                                  float* __restrict__ u, int M) {
    long r0 = (long)blockIdx.x * 128;
    int g0 = segsorted[r0];
    int g1 = segsorted[r0 + 127];
    int t = threadIdx.x;
    float4 z = {0.f, 0.f, 0.f, 0.f};
    float4* p0 = (float4*)(u + (long)g0 * 2048);
    float4* p1 = (float4*)(u + (long)g1 * 2048);
    p0[t] = z; p0[t + 256] = z;
    p1[t] = z; p1[t + 256] = z;
}

// ---------------- B-panel stage: 32 KB linear global->LDS (pre-swz source) ----------------
__device__ __forceinline__ void stageB(const _Float16* __restrict__ src, char* dst, int t) {
    const char* g = (const char*)src;
    #pragma unroll
    for (int i = 0; i < 4; ++i) {
        int off = i * 8192 + t * 16;
        __builtin_amdgcn_global_load_lds(
            (const __attribute__((address_space(1))) unsigned int*)(g + off),
            (__attribute__((address_space(3))) unsigned int*)(dst + off),
            16, 0, 0);
    }
}

// ---------------- flush helper: by-value keeps everything in VGPRs ----------------
__device__ __forceinline__ void flush_u(float* __restrict__ u, float* __restrict__ segsum,
                                        int g, int gl0, int ghi, int h, int l,
                                        f32x4 a0, float se)
{
    bool bd = (g == gl0) || (g == ghi);
    float* d0 = u + (long)g * 2048 + h * 256 + l * 4;
    if (bd) {
        atomicAdd(d0 + 0, a0[0]); atomicAdd(d0 + 1, a0[1]);
        atomicAdd(d0 + 2, a0[2]); atomicAdd(d0 + 3, a0[3]);
    } else {
        *(f32x4*)d0 = a0;
    }
    if (l == 0) {
        float* ds = segsum + (long)g * 8 + h;
        if (bd) atomicAdd(ds, se); else *ds = se;
    }
}

// ---------------- fused: panel-GEMM scores (B from LDS, dbuf) + weighted segment-sum ----
// 8 waves; wave w owns rows w*16..w*16+15 for scores, head w for wsum.
__global__ __launch_bounds__(512) void k_score_wsum(
    const float* __restrict__ msg, const int* __restrict__ sorted,
    const int* __restrict__ segsorted, const _Float16* __restrict__ wqkT,
    float* __restrict__ u, float* __restrict__ segsum, int M)
{
    __shared__ _Float16 At[128 * 256];      // 64 KB, XOR-swizzled
    __shared__ _Float16 Bt[2][64 * 256];    // 2 x 32 KB dbuf (swz via pre-swz source)
    __shared__ float e_lds[128][8];         // 4 KB
    __shared__ int s_sg[128];
    char* ldsA = (char*)At;
    const int t = threadIdx.x;

    // bijective XCD-chunked swizzle (neighbor blocks share boundary segs -> same L2)
    int nwg = gridDim.x;
    int qc = nwg >> 3, rc = nwg & 7;
    int xcd = blockIdx.x & 7, ofs = blockIdx.x >> 3;
    int blk = ((xcd < rc) ? xcd * (qc + 1) : rc * (qc + 1) + (xcd - rc) * qc) + ofs;
    const long m0 = (long)blk * 128;

    if (t < 128) s_sg[t] = segsorted[m0 + t];

    // stage A: gathered 128x256 f32 -> f16 LDS (swz)
    const float4* msgf4 = (const float4*)msg;
    #pragma unroll
    for (int it = 0; it < 16; ++it) {
        int e4 = it * 512 + t;
        int row = e4 >> 6, c4 = e4 & 63;
        int sid = sorted[m0 + row];
        float4 v = msgf4[(long)sid * 64 + c4];
        half4 hv = {(_Float16)v.x, (_Float16)v.y, (_Float16)v.z, (_Float16)v.w};
        int bb = ((row << 9) + (c4 << 3)) ^ ((row & 7) << 4);
        *(half4*)(ldsA + bb) = hv;
    }
    stageB(wqkT, (char*)Bt[0], t);   // q-panel head 0
    __syncthreads();

    const int w = t >> 6, l = t & 63, lr = l & 15, lk = l >> 4;
    const int arow = w * 16 + lr;
    const f32x4 zero = {0.f, 0.f, 0.f, 0.f};
    int buf = 0;

    #pragma unroll 1
    for (int h = 0; h < 8; ++h) {
        // ---- q-phase: stage k-panel; compute aq from Bt[buf] ----
        stageB(wqkT + (size_t)(8 + h) * 16384, (char*)Bt[buf ^ 1], t);
        f32x4 aq0 = zero, aq1 = zero, aq2 = zero, aq3 = zero;
        {
            const char* Bb = (const char*)Bt[buf];
            #pragma unroll
            for (int k0 = 0; k0 < 8; ++k0) {
                int be = (k0 * 32 + lk * 8) << 1;
                int ab = ((arow << 9) + be) ^ ((arow & 7) << 4);
                half8 a = *(const half8*)(ldsA + ab);
                int bb0 = ((lr << 9) + be) ^ ((lr & 7) << 4);
                half8 b0 = *(const half8*)(Bb + bb0);
                half8 b1 = *(const half8*)(Bb + bb0 + 8192);
                half8 b2 = *(const half8*)(Bb + bb0 + 16384);
                half8 b3 = *(const half8*)(Bb + bb0 + 24576);
                aq0 = MFMA16(a, b0, aq0);
                aq1 = MFMA16(a, b1, aq1);
                aq2 = MFMA16(a, b2, aq2);
                aq3 = MFMA16(a, b3, aq3);
            }
        }
        __syncthreads();
        buf ^= 1;

        // ---- k-phase: stage next q-panel; compute ak; dot -> e ----
        if (h < 7) stageB(wqkT + (size_t)(h + 1) * 16384, (char*)Bt[buf ^ 1], t);
        f32x4 ak0 = zero, ak1 = zero, ak2 = zero, ak3 = zero;
        {
            const char* Bb = (const char*)Bt[buf];
            #pragma unroll
            for (int k0 = 0; k0 < 8; ++k0) {
                int be = (k0 * 32 + lk * 8) << 1;
                int ab = ((arow << 9) + be) ^ ((arow & 7) << 4);
                half8 a = *(const half8*)(ldsA + ab);
                int bb0 = ((lr << 9) + be) ^ ((lr & 7) << 4);
                half8 b0 = *(const half8*)(Bb + bb0);
                half8 b1 = *(const half8*)(Bb + bb0 + 8192);
                half8 b2 = *(const half8*)(Bb + bb0 + 16384);
                half8 b3 = *(const half8*)(Bb + bb0 + 24576);
                ak0 = MFMA16(a, b0, ak0);
                ak1 = MFMA16(a, b1, ak1);
                ak2 = MFMA16(a, b2, ak2);
                ak3 = MFMA16(a, b3, ak3);
            }
        }
        f32x4 p = aq0 * ak0 + aq1 * ak1 + aq2 * ak2 + aq3 * ak3;
        #pragma unroll
        for (int off = 1; off < 16; off <<= 1) {
            p[0] += __shfl_xor(p[0], off);
            p[1] += __shfl_xor(p[1], off);
            p[2] += __shfl_xor(p[2], off);
            p[3] += __shfl_xor(p[3], off);
        }
        if (lr == 0) {
            #pragma unroll
            for (int j = 0; j < 4; ++j) {
                float s = p[j];
                s = (s >= 0.f) ? s : 0.2f * s;
                e_lds[w * 16 + lk * 4 + j][h] = __expf(s);  // |s|<~50 << 88: f32-safe
            }
        }
        __syncthreads();
        buf ^= 1;
    }

    // ---- weighted segment-sum: wave w -> head w; lane owns 4 msg cols ----
    const int gl0 = s_sg[0], ghi = s_sg[127];
    f32x4 a0 = zero;
    float se = 0.f;
    int cur = gl0;

    #pragma unroll 4
    for (int row = 0; row < 128; ++row) {
        int sg = s_sg[row];
        if (sg != cur) {                 // wave-uniform branch
            flush_u(u, segsum, cur, gl0, ghi, w, l, a0, se);
            cur = sg; a0 = zero; se = 0.f;
        }
        int bb = ((row << 9) + (l << 3)) ^ ((row & 7) << 4);
        half4 mv = *(const half4*)(ldsA + bb);
        float e = e_lds[row][w];
        a0[0] += e * (float)mv[0];
        a0[1] += e * (float)mv[1];
        a0[2] += e * (float)mv[2];
        a0[3] += e * (float)mv[3];
        se += e;
    }
    flush_u(u, segsum, cur, gl0, ghi, w, l, a0, se);
}

// ---------------- out = (u/segsum) @ CT^T + bout   (K=2048, chunk==head) ----------------
__global__ __launch_bounds__(256) void k_out2(
    const float* __restrict__ u, const float* __restrict__ segsum,
    const _Float16* __restrict__ CT, const float* __restrict__ bout,
    float* __restrict__ out, int N)
{
    __shared__ _Float16 At[64 * 256];   // 32 KB swizzled, per k-chunk
    char* lds = (char*)At;
    const int t = threadIdx.x;
    const long n0 = (long)blockIdx.x * 64;
    const int w = t >> 6, l = t & 63, lr = l & 15, lk = l >> 4;
    const f32x4 zero = {0.f, 0.f, 0.f, 0.f};

    f32x4 ac[4][4];
    #pragma unroll
    for (int r = 0; r < 4; ++r)
        #pragma unroll
        for (int n = 0; n < 4; ++n) ac[r][n] = zero;

    #pragma unroll 1
    for (int kc = 0; kc < 8; ++kc) {    // k-chunk == head
        __syncthreads();
        #pragma unroll
        for (int it = 0; it < 16; ++it) {
            int e4 = it * 256 + t;
            int row = e4 >> 6, c4 = e4 & 63;
            long gr = n0 + row;
            float4 v = {0.f, 0.f, 0.f, 0.f};
            float inv = 0.f;
            if (gr < N) {
                v = ((const float4*)u)[gr * 512 + kc * 64 + c4];
                float ss = segsum[gr * 8 + kc];
                inv = (ss > 0.f) ? 1.f / ss : 0.f;
            }
            half4 hv = {(_Float16)(v.x * inv), (_Float16)(v.y * inv),
                        (_Float16)(v.z * inv), (_Float16)(v.w * inv)};
            int bb = ((row << 9) + (c4 << 3)) ^ ((row & 7) << 4);
            *(half4*)(lds + bb) = hv;
        }
        __syncthreads();
        #pragma unroll
        for (int k0 = 0; k0 < 8; ++k0) {
            half8 a[4];
            #pragma unroll
            for (int r = 0; r < 4; ++r) {
                int row = r * 16 + lr;
                int bb = ((row << 9) + ((k0 * 32 + lk * 8) << 1)) ^ ((row & 7) << 4);
                a[r] = *(const half8*)(lds + bb);
            }
            #pragma unroll
            for (int n = 0; n < 4; ++n) {
                half8 bw = *(const half8*)(CT + ((long)(w * 64 + n * 16 + lr) << 11)
                                              + kc * 256 + k0 * 32 + lk * 8);
                #pragma unroll
                for (int r = 0; r < 4; ++r)
                    ac[r][n] = MFMA16(a[r], bw, ac[r][n]);
            }
        }
    }
    #pragma unroll
    for (int n = 0; n < 4; ++n) {
        int col = w * 64 + n * 16 + lr;
        float bb = bout[col];
        #pragma unroll
        for (int r = 0; r < 4; ++r) {
            #pragma unroll
            for (int j = 0; j < 4; ++j) {
                long row = n0 + r * 16 + lk * 4 + j;
                if (row < N) out[row * 256 + col] = ac[r][n][j] + bb;
            }
        }
    }
}

extern "C" void kernel_launch(void* const* d_in, const int* in_sizes, int n_in,
                              void* d_out, int out_size, void* d_ws, size_t ws_size,
                              hipStream_t stream)
{
    const float* msg   = (const float*)d_in[0];
    const int*   index = (const int*)d_in[1];
    const float* Wq    = (const float*)d_in[4];
    const float* Wk    = (const float*)d_in[5];
    const float* Wv    = (const float*)d_in[6];
    const float* Wout  = (const float*)d_in[7];
    const float* bout  = (const float*)d_in[8];
    float* out = (float*)d_out;

    const int M = in_sizes[0] / 256;   // 400000
    const int N = out_size / 256;      // 50000
    const int NC = (N + 1023) / 1024;  // 49 scan chunks

    char* ws = (char*)d_ws;
    _Float16* wqkT = (_Float16*)(ws);              // 524288 B
    _Float16* CT   = (_Float16*)(ws + 524288);     // 1048576 B
    size_t o2 = 1572864;
    float* segsum = (float*)(ws + o2);                         // N*32
    int* counts   = (int*)(ws + o2 + (size_t)N * 32);          // N*4
    size_t uoff   = (o2 + (size_t)N * 36 + 255) & ~(size_t)255;
    float* u      = (float*)(ws + uoff);                       // N*8192
    size_t p2     = uoff + (size_t)N * 8192;
    int* cursor    = (int*)(ws + p2);                          // N*4
    int* starts    = (int*)(ws + p2 + (size_t)N * 4);          // (N+1)*4
    char* p3       = ws + p2 + (((size_t)N * 8 + 4 + 63) & ~(size_t)63);
    int* sorted    = (int*)(p3);                               // M*4
    int* segsorted = (int*)(p3 + (size_t)M * 4);               // M*4
    int* blocktot  = (int*)(p3 + (size_t)M * 8);               // 256 B
    int* blockoff  = (int*)(p3 + (size_t)M * 8 + 256);         // 256 B

    // zero only segsum + counts; boundary u rows zeroed by k_zero_bnd;
    // empty-seg u rows masked by inv=0 in k_out2 (poison is finite)
    hipMemsetAsync(ws + o2, 0, (size_t)N * 36, stream);

    k_convert<<<512, 256, 0, stream>>>(Wq, Wk, wqkT);
    k_convC<<<512, 256, 0, stream>>>(Wv, Wout, CT);
    k_hist<<<(M + 255) / 256, 256, 0, stream>>>(index, counts, M);
    k_scan1<<<NC, 1024, 0, stream>>>(counts, starts, blocktot, N);
    k_scan2<<<1, 64, 0, stream>>>(blocktot, blockoff, NC);
    k_scan3<<<NC, 1024, 0, stream>>>(starts, cursor, blockoff, N, M);
    k_scatteridx<<<(M + 255) / 256, 256, 0, stream>>>(index, cursor, sorted, segsorted, M);
    k_zero_bnd<<<M / 128, 256, 0, stream>>>(segsorted, u, M);
    k_score_wsum<<<M / 128, 512, 0, stream>>>(msg, sorted, segsorted, wqkT, u, segsum, M);
    k_out2<<<(N + 63) / 64, 256, 0, stream>>>(u, segsum, CT, bout, out, N);
}

// Round 10
// 1148.005 us; speedup vs baseline: 2.0735x; 1.0360x over previous
//
#include <hip/hip_runtime.h>
#include <hip/hip_bf16.h>

typedef _Float16 half8 __attribute__((ext_vector_type(8)));
typedef _Float16 half4 __attribute__((ext_vector_type(4)));
typedef float f32x4 __attribute__((ext_vector_type(4)));

// Geometry: D=256, H=8, A=64, M=400000 (128*3125), N=50000
// Algebra: out_g = sum_h (u_{g,h}/s_{g,h}) @ (Wv_h @ Wout_h) + bout
//          u_{g,h} = sum_{m in g} e_{m,h} * msg_m

#define MFMA16(a, b, c) __builtin_amdgcn_mfma_f32_16x16x32_f16(a, b, c, 0, 0, 0)

// ---------------- wqkT panels in FRAGMENT ORDER ----------------
// panel p (q:h, k:8+h), element (col a, k d):
//   k0=d>>5, lk=(d>>3)&3, j=d&7, cb=a>>4, lr=a&15, lane l=lk*16+lr
//   half index = (k0*4+cb)*512 + l*8 + j   (each (k0,cb) chunk = 64 lanes x 16B)
__global__ void k_convert(const float* __restrict__ Wq, const float* __restrict__ Wk,
                          _Float16* __restrict__ wqkT)
{
    int gid = blockIdx.x * 256 + threadIdx.x;   // 131072
    int h = gid >> 14;
    int d = (gid >> 6) & 255;
    int a = gid & 63;
    int k0 = d >> 5, lk = (d >> 3) & 3, j = d & 7;
    int cb = a >> 4, lr = a & 15;
    int idx = ((k0 * 4 + cb) * 64 + lk * 16 + lr) * 8 + j;
    wqkT[h * 16384 + idx]       = (_Float16)Wq[gid];
    wqkT[(8 + h) * 16384 + idx] = (_Float16)Wk[gid];
}

// ---------------- CT = Wv_h @ Wout_h in FRAGMENT ORDER ----------------
// B-frag for k_out2: out-col c=nb*16+lr, k=kc*256+k0*32+lk*8+j
//   half index = ((nb*8+kc)*8+k0)*512 + (lk*16+lr)*8 + j
__global__ void k_convC(const float* __restrict__ Wv, const float* __restrict__ Wout,
                        _Float16* __restrict__ CT)
{
    __shared__ float wv[4][64];
    int h = blockIdx.x >> 6, din0 = (blockIdx.x & 63) << 2;
    int t = threadIdx.x;
    wv[t >> 6][t & 63] = Wv[((h << 8) + din0 + (t >> 6)) * 64 + (t & 63)];
    __syncthreads();
    float s[4] = {0.f, 0.f, 0.f, 0.f};
    for (int a = 0; a < 64; ++a) {
        float wo = Wout[(h * 64 + a) * 256 + t];
        #pragma unroll
        for (int dd = 0; dd < 4; ++dd) s[dd] += wv[dd][a] * wo;
    }
    int nb = t >> 4, lr = t & 15;
    #pragma unroll
    for (int dd = 0; dd < 4; ++dd) {
        int din = din0 + dd;
        int k0 = din >> 5, lk = (din >> 3) & 3, j = din & 7;
        CT[(size_t)((nb * 8 + h) * 8 + k0) * 512 + (lk * 16 + lr) * 8 + j] = (_Float16)s[dd];
    }
}

// ---------------- counting sort ----------------
__global__ void k_hist(const int* __restrict__ index, int* __restrict__ counts, int M) {
    int m = blockIdx.x * 256 + threadIdx.x;
    if (m < M) atomicAdd(&counts[index[m]], 1);
}

__global__ __launch_bounds__(1024) void k_scan1(const int* __restrict__ counts,
                                                int* __restrict__ starts,
                                                int* __restrict__ blocktot, int N) {
    __shared__ int s[1024];
    int b = blockIdx.x, t = threadIdx.x;
    int i = b * 1024 + t;
    int x = (i < N) ? counts[i] : 0;
    s[t] = x;
    __syncthreads();
    #pragma unroll
    for (int off = 1; off < 1024; off <<= 1) {
        int v = (t >= off) ? s[t - off] : 0;
        __syncthreads();
        s[t] += v;
        __syncthreads();
    }
    if (i < N) starts[i] = s[t] - x;
    if (t == 1023) blocktot[b] = s[1023];
}

__global__ void k_scan2(const int* __restrict__ blocktot, int* __restrict__ blockoff, int NC) {
    if (threadIdx.x == 0 && blockIdx.x == 0) {
        int run = 0;
        for (int i = 0; i < NC; ++i) { blockoff[i] = run; run += blocktot[i]; }
    }
}

__global__ __launch_bounds__(1024) void k_scan3(int* __restrict__ starts,
                                                int* __restrict__ cursor,
                                                const int* __restrict__ blockoff,
                                                int N, int M) {
    int b = blockIdx.x, t = threadIdx.x;
    int i = b * 1024 + t;
    if (i < N) {
        int v = starts[i] + blockoff[b];
        starts[i] = v;
        cursor[i] = v;
    }
    if (b == 0 && t == 0) starts[N] = M;
}

__global__ void k_scatteridx(const int* __restrict__ index, int* __restrict__ cursor,
                             int* __restrict__ sorted, int* __restrict__ segsorted, int M) {
    int m = blockIdx.x * 256 + threadIdx.x;
    if (m < M) {
        int idx = index[m];
        int pos = atomicAdd(&cursor[idx], 1);
        sorted[pos] = m;
        segsorted[pos] = idx;
    }
}

// ---------------- zero u rows of block-boundary segments ----------------
__global__ __launch_bounds__(256) void k_zero_bnd(const int* __restrict__ segsorted,
                                                  float* __restrict__ u, int M) {
    long r0 = (long)blockIdx.x * 128;
    int g0 = segsorted[r0];
    int g1 = segsorted[r0 + 127];
    int t = threadIdx.x;
    float4 z = {0.f, 0.f, 0.f, 0.f};
    float4* p0 = (float4*)(u + (long)g0 * 2048);
    float4* p1 = (float4*)(u + (long)g1 * 2048);
    p0[t] = z; p0[t + 256] = z;
    p1[t] = z; p1[t + 256] = z;
}

// ---------------- B-panel stage: 32 KB linear global->LDS ----------------
__device__ __forceinline__ void stageB(const _Float16* __restrict__ src, char* dst, int t) {
    const char* g = (const char*)src;
    #pragma unroll
    for (int i = 0; i < 4; ++i) {
        int off = i * 8192 + t * 16;
        __builtin_amdgcn_global_load_lds(
            (const __attribute__((address_space(1))) unsigned int*)(g + off),
            (__attribute__((address_space(3))) unsigned int*)(dst + off),
            16, 0, 0);
    }
}

// ---------------- flush helper ----------------
__device__ __forceinline__ void flush_u(float* __restrict__ u, float* __restrict__ segsum,
                                        int g, int gl0, int ghi, int h, int l,
                                        f32x4 a0, float se)
{
    bool bd = (g == gl0) || (g == ghi);
    float* d0 = u + (long)g * 2048 + h * 256 + l * 4;
    if (bd) {
        atomicAdd(d0 + 0, a0[0]); atomicAdd(d0 + 1, a0[1]);
        atomicAdd(d0 + 2, a0[2]); atomicAdd(d0 + 3, a0[3]);
    } else {
        *(f32x4*)d0 = a0;
    }
    if (l == 0) {
        float* ds = segsum + (long)g * 8 + h;
        if (bd) atomicAdd(ds, se); else *ds = se;
    }
}

// ---------------- fused: A-frags-in-reg panel GEMM + weighted segment-sum ----------------
// 8 waves; wave w: row-group w&3 (32 rows), col-group w>>2 (32 of 64 proj cols).
// Cross-wave dot combine via ptmp. wsum: wave w = head w.
__global__ __launch_bounds__(512) void k_score_wsum(
    const float* __restrict__ msg, const int* __restrict__ sorted,
    const int* __restrict__ segsorted, const _Float16* __restrict__ wqkT,
    float* __restrict__ u, float* __restrict__ segsum, int M)
{
    __shared__ __align__(16) _Float16 At[128 * 256];     // 64 KB, XOR-swz row-major
    __shared__ __align__(16) _Float16 Bt[2][64 * 256];   // 2 x 32 KB, fragment order
    __shared__ float e_lds[128][9];                      // 4608 B (pad 9: conflict-free)
    __shared__ float ptmp[2][128];                       // 1 KB
    __shared__ int s_id[128];
    __shared__ int s_sg[128];
    char* ldsA = (char*)At;
    const int t = threadIdx.x;

    // bijective XCD-chunked swizzle (neighbor blocks share boundary segs -> same L2)
    int nwg = gridDim.x;
    int qc = nwg >> 3, rc = nwg & 7;
    int xcd = blockIdx.x & 7, ofs = blockIdx.x >> 3;
    int blk = ((xcd < rc) ? xcd * (qc + 1) : rc * (qc + 1) + (xcd - rc) * qc) + ofs;
    const long m0 = (long)blk * 128;

    if (t < 128) {
        s_id[t] = sorted[m0 + t];
        s_sg[t] = segsorted[m0 + t];
    }
    __syncthreads();

    // stage A: gathered 128x256 f32 -> f16 LDS (swz)
    const float4* msgf4 = (const float4*)msg;
    #pragma unroll
    for (int it = 0; it < 16; ++it) {
        int e4 = it * 512 + t;
        int row = e4 >> 6, c4 = e4 & 63;
        float4 v = msgf4[(long)s_id[row] * 64 + c4];
        half4 hv = {(_Float16)v.x, (_Float16)v.y, (_Float16)v.z, (_Float16)v.w};
        int bb = ((row << 9) + (c4 << 3)) ^ ((row & 7) << 4);
        *(half4*)(ldsA + bb) = hv;
    }
    stageB(wqkT, (char*)Bt[0], t);   // q-panel head 0
    __syncthreads();

    const int w = t >> 6, l = t & 63, lr = l & 15, lk = l >> 4;
    const int rowg = w & 3, colg = w >> 2;
    const int cbg = colg * 2;
    const f32x4 zero = {0.f, 0.f, 0.f, 0.f};

    // ---- A-fragments to registers (64 VGPR), reused for all 16 panels ----
    half8 af[2][8];
    #pragma unroll
    for (int rb = 0; rb < 2; ++rb) {
        int arow = rowg * 32 + rb * 16 + lr;
        #pragma unroll
        for (int k0 = 0; k0 < 8; ++k0) {
            int bb = ((arow << 9) + (k0 * 64 + lk * 16)) ^ ((arow & 7) << 4);
            af[rb][k0] = *(const half8*)(ldsA + bb);
        }
    }

    int buf = 0;
    #pragma unroll 1
    for (int h = 0; h < 8; ++h) {
        // ---- q sub-phase: compute from Bt[buf]; stage k-panel ----
        stageB(wqkT + (size_t)(8 + h) * 16384, (char*)Bt[buf ^ 1], t);
        f32x4 aq00 = zero, aq01 = zero, aq10 = zero, aq11 = zero;
        {
            const char* Bb = (const char*)Bt[buf];
            #pragma unroll
            for (int k0 = 0; k0 < 8; ++k0) {
                half8 b0 = *(const half8*)(Bb + (k0 * 4 + cbg) * 1024 + l * 16);
                half8 b1 = *(const half8*)(Bb + (k0 * 4 + cbg + 1) * 1024 + l * 16);
                aq00 = MFMA16(af[0][k0], b0, aq00);
                aq01 = MFMA16(af[0][k0], b1, aq01);
                aq10 = MFMA16(af[1][k0], b0, aq10);
                aq11 = MFMA16(af[1][k0], b1, aq11);
            }
        }
        __syncthreads();
        buf ^= 1;

        // ---- k sub-phase: compute from Bt[buf]; stage next q-panel; dot ----
        if (h < 7) stageB(wqkT + (size_t)(h + 1) * 16384, (char*)Bt[buf ^ 1], t);
        f32x4 ak00 = zero, ak01 = zero, ak10 = zero, ak11 = zero;
        {
            const char* Bb = (const char*)Bt[buf];
            #pragma unroll
            for (int k0 = 0; k0 < 8; ++k0) {
                half8 b0 = *(const half8*)(Bb + (k0 * 4 + cbg) * 1024 + l * 16);
                half8 b1 = *(const half8*)(Bb + (k0 * 4 + cbg + 1) * 1024 + l * 16);
                ak00 = MFMA16(af[0][k0], b0, ak00);
                ak01 = MFMA16(af[0][k0], b1, ak01);
                ak10 = MFMA16(af[1][k0], b0, ak10);
                ak11 = MFMA16(af[1][k0], b1, ak11);
            }
        }
        f32x4 p0 = aq00 * ak00 + aq01 * ak01;   // partial over this wave's 32 cols
        f32x4 p1 = aq10 * ak10 + aq11 * ak11;
        #pragma unroll
        for (int off = 1; off < 16; off <<= 1) {
            p0[0] += __shfl_xor(p0[0], off); p0[1] += __shfl_xor(p0[1], off);
            p0[2] += __shfl_xor(p0[2], off); p0[3] += __shfl_xor(p0[3], off);
            p1[0] += __shfl_xor(p1[0], off); p1[1] += __shfl_xor(p1[1], off);
            p1[2] += __shfl_xor(p1[2], off); p1[3] += __shfl_xor(p1[3], off);
        }
        if (lr == 0) {
            #pragma unroll
            for (int j = 0; j < 4; ++j) {
                ptmp[colg][rowg * 32 + lk * 4 + j]      = p0[j];
                ptmp[colg][rowg * 32 + 16 + lk * 4 + j] = p1[j];
            }
        }
        __syncthreads();   // ptmp visible; Bt[buf] free; next-q staged
        if (colg == 0 && l < 32) {
            int row = rowg * 32 + l;
            float s = ptmp[0][row] + ptmp[1][row];
            s = (s >= 0.f) ? s : 0.2f * s;
            e_lds[row][h] = __expf(s);   // |s| <~ 50 << 88: f32-safe
        }
        __syncthreads();   // combine done before next ptmp overwrite
        buf ^= 1;
    }

    // ---- weighted segment-sum: wave w -> head w; lane owns 4 msg cols ----
    const int gl0 = s_sg[0], ghi = s_sg[127];
    f32x4 a0 = zero;
    float se = 0.f;
    int cur = gl0;

    #pragma unroll 4
    for (int row = 0; row < 128; ++row) {
        int sg = s_sg[row];
        if (sg != cur) {                 // wave-uniform branch
            flush_u(u, segsum, cur, gl0, ghi, w, l, a0, se);
            cur = sg; a0 = zero; se = 0.f;
        }
        int bb = ((row << 9) + (l << 3)) ^ ((row & 7) << 4);
        half4 mv = *(const half4*)(ldsA + bb);
        float e = e_lds[row][w];
        a0[0] += e * (float)mv[0];
        a0[1] += e * (float)mv[1];
        a0[2] += e * (float)mv[2];
        a0[3] += e * (float)mv[3];
        se += e;
    }
    flush_u(u, segsum, cur, gl0, ghi, w, l, a0, se);
}

// ---------------- out = (u/segsum) @ CT + bout (CT frag-order, coalesced L2) ----------------
__global__ __launch_bounds__(256) void k_out2(
    const float* __restrict__ u, const float* __restrict__ segsum,
    const _Float16* __restrict__ CT, const float* __restrict__ bout,
    float* __restrict__ out, int N)
{
    __shared__ _Float16 At[64 * 256];   // 32 KB swizzled, per k-chunk
    char* lds = (char*)At;
    const int t = threadIdx.x;
    const long n0 = (long)blockIdx.x * 64;
    const int w = t >> 6, l = t & 63, lr = l & 15, lk = l >> 4;
    const f32x4 zero = {0.f, 0.f, 0.f, 0.f};

    f32x4 ac[4][4];
    #pragma unroll
    for (int r = 0; r < 4; ++r)
        #pragma unroll
        for (int n = 0; n < 4; ++n) ac[r][n] = zero;

    #pragma unroll 1
    for (int kc = 0; kc < 8; ++kc) {    // k-chunk == head
        __syncthreads();
        #pragma unroll
        for (int it = 0; it < 16; ++it) {
            int e4 = it * 256 + t;
            int row = e4 >> 6, c4 = e4 & 63;
            long gr = n0 + row;
            float4 v = {0.f, 0.f, 0.f, 0.f};
            float inv = 0.f;
            if (gr < N) {
                v = ((const float4*)u)[gr * 512 + kc * 64 + c4];
                float ss = segsum[gr * 8 + kc];
                inv = (ss > 0.f) ? 1.f / ss : 0.f;
            }
            half4 hv = {(_Float16)(v.x * inv), (_Float16)(v.y * inv),
                        (_Float16)(v.z * inv), (_Float16)(v.w * inv)};
            int bb = ((row << 9) + (c4 << 3)) ^ ((row & 7) << 4);
            *(half4*)(lds + bb) = hv;
        }
        __syncthreads();
        #pragma unroll
        for (int k0 = 0; k0 < 8; ++k0) {
            half8 a[4];
            #pragma unroll
            for (int r = 0; r < 4; ++r) {
                int row = r * 16 + lr;
                int bb = ((row << 9) + ((k0 * 32 + lk * 8) << 1)) ^ ((row & 7) << 4);
                a[r] = *(const half8*)(lds + bb);
            }
            #pragma unroll
            for (int n = 0; n < 4; ++n) {
                // frag-order CT: 64 lanes x 16B contiguous (coalesced L2 read)
                half8 bw = *(const half8*)(CT +
                    (size_t)(((w * 4 + n) * 8 + kc) * 8 + k0) * 512 + l * 8);
                #pragma unroll
                for (int r = 0; r < 4; ++r)
                    ac[r][n] = MFMA16(a[r], bw, ac[r][n]);
            }
        }
    }
    #pragma unroll
    for (int n = 0; n < 4; ++n) {
        int col = w * 64 + n * 16 + lr;
        float bb = bout[col];
        #pragma unroll
        for (int r = 0; r < 4; ++r) {
            #pragma unroll
            for (int j = 0; j < 4; ++j) {
                long row = n0 + r * 16 + lk * 4 + j;
                if (row < N) out[row * 256 + col] = ac[r][n][j] + bb;
            }
        }
    }
}

extern "C" void kernel_launch(void* const* d_in, const int* in_sizes, int n_in,
                              void* d_out, int out_size, void* d_ws, size_t ws_size,
                              hipStream_t stream)
{
    const float* msg   = (const float*)d_in[0];
    const int*   index = (const int*)d_in[1];
    const float* Wq    = (const float*)d_in[4];
    const float* Wk    = (const float*)d_in[5];
    const float* Wv    = (const float*)d_in[6];
    const float* Wout  = (const float*)d_in[7];
    const float* bout  = (const float*)d_in[8];
    float* out = (float*)d_out;

    const int M = in_sizes[0] / 256;   // 400000
    const int N = out_size / 256;      // 50000
    const int NC = (N + 1023) / 1024;  // 49 scan chunks

    char* ws = (char*)d_ws;
    _Float16* wqkT = (_Float16*)(ws);              // 524288 B
    _Float16* CT   = (_Float16*)(ws + 524288);     // 1048576 B
    size_t o2 = 1572864;
    float* segsum = (float*)(ws + o2);                         // N*32
    int* counts   = (int*)(ws + o2 + (size_t)N * 32);          // N*4
    size_t uoff   = (o2 + (size_t)N * 36 + 255) & ~(size_t)255;
    float* u      = (float*)(ws + uoff);                       // N*8192
    size_t p2     = uoff + (size_t)N * 8192;
    int* cursor    = (int*)(ws + p2);                          // N*4
    int* starts    = (int*)(ws + p2 + (size_t)N * 4);          // (N+1)*4
    char* p3       = ws + p2 + (((size_t)N * 8 + 4 + 63) & ~(size_t)63);
    int* sorted    = (int*)(p3);                               // M*4
    int* segsorted = (int*)(p3 + (size_t)M * 4);               // M*4
    int* blocktot  = (int*)(p3 + (size_t)M * 8);               // 256 B
    int* blockoff  = (int*)(p3 + (size_t)M * 8 + 256);         // 256 B

    // zero only segsum + counts; boundary u rows zeroed by k_zero_bnd;
    // empty-seg u rows masked by inv=0 in k_out2 (poison is finite)
    hipMemsetAsync(ws + o2, 0, (size_t)N * 36, stream);

    k_convert<<<512, 256, 0, stream>>>(Wq, Wk, wqkT);
    k_convC<<<512, 256, 0, stream>>>(Wv, Wout, CT);
    k_hist<<<(M + 255) / 256, 256, 0, stream>>>(index, counts, M);
    k_scan1<<<NC, 1024, 0, stream>>>(counts, starts, blocktot, N);
    k_scan2<<<1, 64, 0, stream>>>(blocktot, blockoff, NC);
    k_scan3<<<NC, 1024, 0, stream>>>(starts, cursor, blockoff, N, M);
    k_scatteridx<<<(M + 255) / 256, 256, 0, stream>>>(index, cursor, sorted, segsorted, M);
    k_zero_bnd<<<M / 128, 256, 0, stream>>>(segsorted, u, M);
    k_score_wsum<<<M / 128, 512, 0, stream>>>(msg, sorted, segsorted, wqkT, u, segsum, M);
    k_out2<<<(N + 63) / 64, 256, 0, stream>>>(u, segsum, CT, bout, out, N);
}